// Round 14
// baseline (1344.044 us; speedup 1.0000x reference)
//
#include <hip/hip_runtime.h>

typedef __attribute__((ext_vector_type(8))) short bf16x8;
typedef __attribute__((ext_vector_type(4))) float f32x4;

#define T_STEPS 96
#define BATCH 64
#define HID 2048

#define AS1 __attribute__((address_space(1)))
#define AS3 __attribute__((address_space(3)))
#define MFMA16(a, b, c) __builtin_amdgcn_mfma_f32_16x16x32_bf16(a, b, c, 0, 0, 0)

__device__ inline unsigned short f2bf(float f) {
  union { float f; unsigned u; } x; x.f = f;
  unsigned r = x.u + 0x7fffu + ((x.u >> 16) & 1u);
  return (unsigned short)(r >> 16);
}
__device__ inline float bf2f(unsigned short b) {
  union { unsigned u; float f; } x; x.u = ((unsigned)b) << 16;
  return x.f;
}
__device__ inline float sigm(float x) { return 1.f / (1.f + __expf(-x)); }
__device__ inline float tanh_(float x) { return 1.f - 2.f / (__expf(2.f * x) + 1.f); }

// ---------------------------------------------------------------- cast f32->bf16
__global__ __launch_bounds__(256) void cast_bf16(const float* __restrict__ in,
                                                 unsigned short* __restrict__ out,
                                                 int n4) {
  int i = blockIdx.x * 256 + threadIdx.x;
  if (i >= n4) return;
  float4 v = ((const float4*)in)[i];
  ushort4 o;
  o.x = f2bf(v.x); o.y = f2bf(v.y); o.z = f2bf(v.z); o.w = f2bf(v.w);
  ((ushort4*)out)[i] = o;
}

// ---------------------------------------------------------------- gumbel (threefry, partitionable)
__global__ void gumbel_k(float* __restrict__ g) {
  int p = blockIdx.x * blockDim.x + threadIdx.x;
  if (p >= 12288) return;
  const unsigned k1 = 0u, k2 = 42u;
  unsigned ks[3] = { k1, k2, 0x1BD11BDAu ^ k1 ^ k2 };
  unsigned x0 = 0u + ks[0];
  unsigned x1 = (unsigned)p + ks[1];
  const int rot[2][4] = { {13, 15, 26, 6}, {17, 29, 16, 24} };
  #pragma unroll
  for (int i = 0; i < 5; ++i) {
    #pragma unroll
    for (int j = 0; j < 4; ++j) {
      int r = rot[i & 1][j];
      x0 += x1;
      x1 = (x1 << r) | (x1 >> (32 - r));
      x1 ^= x0;
    }
    x0 += ks[(i + 1) % 3];
    x1 += ks[(i + 2) % 3] + (unsigned)(i + 1);
  }
  unsigned bits = x0 ^ x1;
  union { unsigned u; float f; } v; v.u = (bits >> 9) | 0x3f800000u;
  float f = v.f - 1.f;
  const float tiny = 1.17549435e-38f;
  float u = fmaxf(tiny, f * (1.f - tiny) + tiny);
  g[p] = -logf(-logf(u));
}

// ---------------------------------------------------------------- phase-1 GEMM
// 128x128 tile, BK=64 in 2 K-half phases, 256 threads = 4 waves (2Mx2N,
// wave tile 64x64). LDS 64 KB (2 dbuf x 2 khalf x (A8K|B8K)) -> 2 blocks/CU:
// co-resident block overlaps stage with compute (the R10 structure's missing
// piece -- it had 128 KB -> 1 block/CU and stalled CU-wide on every barrier).
// Counted vmcnt identical to R10: prologue 8 loads; ph0 waits vmcnt(4)
// (newest 4 = S(t,1)), in-loop stage t+1 (8 loads), ph1 waits vmcnt(8)
// (newest 8 = S(t+1,*)). Both-sides swizzle kbyte^=((row&3)<<4).
__global__ __launch_bounds__(256, 2) void gemm_xg(
    const unsigned short* __restrict__ A,
    const unsigned short* __restrict__ W,
    const float* __restrict__ b_ih, const float* __restrict__ b_hh,
    unsigned short* __restrict__ xg) {
  extern __shared__ unsigned char smem[];   // 64 KB
  const int bid = blockIdx.x;
  const int swz = (bid & 7) * 384 + (bid >> 3);  // bijective (3072 = 8*384)
  const int mb = swz >> 6, nb = swz & 63;        // 48 x 64 tiles, nb fastest
  const int m0 = mb * 128, n0 = nb * 128;
  const int tid = threadIdx.x;
  const int l = tid & 63;
  const int w = tid >> 6;
  const int lr = l & 15, lg = l >> 4;
  const int wm = w >> 1, wn = w & 1;

  // stage S(t,h): A-half (2 loads) + B-half (2 loads); half = 128 rows x 32 K
#define XSTAGE(dd, hh, tt) do {                                                 \
    _Pragma("unroll")                                                           \
    for (int r_ = 0; r_ < 2; ++r_) {                                            \
      int slot_ = r_ * 256 + tid;                                               \
      int row_ = slot_ >> 2;                                                    \
      int kby_ = ((slot_ & 3) * 16) ^ ((row_ & 3) << 4);                        \
      const unsigned short* sa_ =                                               \
          A + (long)(m0 + row_) * 2048 + (tt) * 64 + (hh) * 32 + (kby_ >> 1);   \
      __builtin_amdgcn_global_load_lds((const AS1 unsigned int*)sa_,            \
          (AS3 unsigned int*)(smem + (dd) * 32768 + (hh) * 16384 + slot_ * 16), \
          16, 0, 0);                                                            \
    }                                                                           \
    _Pragma("unroll")                                                           \
    for (int r_ = 0; r_ < 2; ++r_) {                                            \
      int slot_ = r_ * 256 + tid;                                               \
      int row_ = slot_ >> 2;                                                    \
      int kby_ = ((slot_ & 3) * 16) ^ ((row_ & 3) << 4);                        \
      const unsigned short* sb_ =                                               \
          W + (long)(n0 + row_) * 2048 + (tt) * 64 + (hh) * 32 + (kby_ >> 1);   \
      __builtin_amdgcn_global_load_lds((const AS1 unsigned int*)sb_,            \
          (AS3 unsigned int*)(smem + (dd) * 32768 + (hh) * 16384 + 8192 +       \
                              slot_ * 16), 16, 0, 0);                           \
    }                                                                           \
  } while (0)

  f32x4 acc[4][4] = {};
  const int kxa = (lr & 3) << 4;

  // one phase: 8 ds_read_b128 -> 16 MFMA (4 a-frags x 4 b-frags, one K=32 step)
#define XPHASE(dd, hh) do {                                                     \
    const unsigned char* ba_ = smem + (dd) * 32768 + (hh) * 16384;              \
    const unsigned char* bb_ = ba_ + 8192;                                      \
    bf16x8 a_[4], b_[4];                                                        \
    _Pragma("unroll")                                                           \
    for (int mf_ = 0; mf_ < 4; ++mf_)                                           \
      a_[mf_] = *(const bf16x8*)(ba_ + (wm * 64 + mf_ * 16 + lr) * 64 +         \
                                 ((lg * 16) ^ kxa));                            \
    _Pragma("unroll")                                                           \
    for (int nf_ = 0; nf_ < 4; ++nf_)                                           \
      b_[nf_] = *(const bf16x8*)(bb_ + (wn * 64 + nf_ * 16 + lr) * 64 +         \
                                 ((lg * 16) ^ kxa));                            \
    __builtin_amdgcn_s_setprio(1);                                              \
    _Pragma("unroll")                                                           \
    for (int mf_ = 0; mf_ < 4; ++mf_)                                           \
      _Pragma("unroll")                                                         \
      for (int nf_ = 0; nf_ < 4; ++nf_)                                         \
        acc[mf_][nf_] = MFMA16(a_[mf_], b_[nf_], acc[mf_][nf_]);                \
    __builtin_amdgcn_s_setprio(0);                                              \
    __builtin_amdgcn_sched_barrier(0);                                          \
  } while (0)

  // prologue: tile 0 (8 loads)
  XSTAGE(0, 0, 0);
  XSTAGE(0, 1, 0);
  __builtin_amdgcn_sched_barrier(0);

  for (int t = 0; t < 32; ++t) {
    const int d = t & 1;
    // phase 0: S(t,0) ready when all but newest 4 (=S(t,1)) complete
    asm volatile("s_waitcnt vmcnt(4)" ::: "memory");
    __builtin_amdgcn_s_barrier();
    __builtin_amdgcn_sched_barrier(0);
    XSTAGE(d ^ 1, 0, t + 1);     // t=31 stages past-end (lands in adjacent ws, unused)
    XSTAGE(d ^ 1, 1, t + 1);
    __builtin_amdgcn_sched_barrier(0);
    XPHASE(d, 0);
    // phase 1: S(t,1) ready when all but newest 8 (=S(t+1,*)) complete
    asm volatile("s_waitcnt vmcnt(8)" ::: "memory");
    __builtin_amdgcn_s_barrier();
    __builtin_amdgcn_sched_barrier(0);
    XPHASE(d, 1);
  }
#undef XSTAGE
#undef XPHASE

  // epilogue: bias + t-major store (coalesced 16-lane row segments)
  float bias[4];
  #pragma unroll
  for (int nf = 0; nf < 4; ++nf) {
    int n = n0 + wn * 64 + nf * 16 + lr;
    bias[nf] = b_ih[n] + b_hh[n];
  }
  #pragma unroll
  for (int mf = 0; mf < 4; ++mf) {
    #pragma unroll
    for (int r = 0; r < 4; ++r) {
      int m = m0 + wm * 64 + mf * 16 + lg * 4 + r;
      int bb2 = m / 96;
      int tt = m - bb2 * 96;
      long row = (long)tt * 64 + bb2;
      #pragma unroll
      for (int nf = 0; nf < 4; ++nf) {
        int n = n0 + wn * 64 + nf * 16 + lr;
        xg[row * 8192 + n] = f2bf(acc[mf][nf][r] + bias[nf]);
      }
    }
  }
}

// ---------------------------------------------------------------- recurrent step (R13, kept: ties best)
__global__ __launch_bounds__(512) void lstm_step(
    const unsigned short* __restrict__ Whh,   // (8192,2048) bf16
    const unsigned short* __restrict__ xg,    // (96,64,8192) bf16
    const unsigned short* __restrict__ Hprev, // (64,2048) bf16
    unsigned short* __restrict__ Hnext,       // (64,2048) bf16
    unsigned short* __restrict__ Call_t,      // (64,2048) bf16 snapshot
    float* __restrict__ Cstate,               // (64,2048) f32
    int t) {
  __shared__ unsigned char smem[3 * 24576 + 32768];  // ring (A16K+B8K per buf) + part 32K
  const int cb = blockIdx.x;
  const int tid = threadIdx.x;
  const int w = tid >> 6, l = tid & 63;
  const int lr = l & 15, lg = l >> 4;
  const int mh = w & 1, kq = w >> 1;

  const int lane16 = l & 15, lrow = l >> 4;
  const int rowA0 = w * 4 + lrow;
  const int rowA1 = 32 + rowA0;
  const int rowB  = w * 4 + lrow;
  const int kszA0 = (lane16 * 16) ^ ((rowA0 & 7) << 4);
  const int kszA1 = (lane16 * 16) ^ ((rowA1 & 7) << 4);
  const int kszB  = (lane16 * 16) ^ ((rowB & 7) << 4);
  const int WrowB = (rowB >> 3) * 2048 + cb * 8 + (rowB & 7);
  const unsigned short* aS0 = Hprev + (long)rowA0 * 2048 + (kszA0 >> 1);
  const unsigned short* aS1 = Hprev + (long)rowA1 * 2048 + (kszA1 >> 1);
  const unsigned short* bS  = Whh + (long)WrowB * 2048 + (kszB >> 1);

#define STAGE(bufi, k0) do {                                                    \
    unsigned char* lb = smem + (bufi) * 24576 + w * 1024;                       \
    __builtin_amdgcn_global_load_lds((const AS1 unsigned int*)(aS0 + (k0)),     \
        (AS3 unsigned int*)(lb), 16, 0, 0);                                     \
    __builtin_amdgcn_global_load_lds((const AS1 unsigned int*)(aS1 + (k0)),     \
        (AS3 unsigned int*)(lb + 8192), 16, 0, 0);                              \
    __builtin_amdgcn_global_load_lds((const AS1 unsigned int*)(bS + (k0)),      \
        (AS3 unsigned int*)(lb + 16384), 16, 0, 0);                             \
  } while (0)

  STAGE(0, 0);
  STAGE(1, 128);

  f32x4 acc00 = {}, acc01 = {}, acc10 = {}, acc11 = {};
  const int kx = (lr & 7) << 4;
  const int aOff0 = (mh * 32 + lr) * 256;
  const int aOff1 = (mh * 32 + 16 + lr) * 256;
  const int bOff0 = 16384 + lr * 256;
  const int bOff1 = 16384 + (16 + lr) * 256;
  const int kb = (kq * 64 + lg * 16) ^ kx;

  for (int ks = 0; ks < 16; ++ks) {
    if (ks < 15) asm volatile("s_waitcnt vmcnt(3)" ::: "memory");
    else         asm volatile("s_waitcnt vmcnt(0)" ::: "memory");
    __builtin_amdgcn_s_barrier();
    __builtin_amdgcn_sched_barrier(0);
    if (ks < 14) STAGE((ks + 2) % 3, (ks + 2) * 128);
    const unsigned char* bufp = smem + (ks % 3) * 24576;
    __builtin_amdgcn_s_setprio(1);
    {
      bf16x8 a0 = *(const bf16x8*)(bufp + aOff0 + kb);
      bf16x8 a1 = *(const bf16x8*)(bufp + aOff1 + kb);
      bf16x8 b0 = *(const bf16x8*)(bufp + bOff0 + kb);
      bf16x8 b1 = *(const bf16x8*)(bufp + bOff1 + kb);
      acc00 = MFMA16(a0, b0, acc00);
      acc01 = MFMA16(a0, b1, acc01);
      acc10 = MFMA16(a1, b0, acc10);
      acc11 = MFMA16(a1, b1, acc11);
    }
    __builtin_amdgcn_s_setprio(0);
    __builtin_amdgcn_sched_barrier(0);
  }
#undef STAGE

  float* part = (float*)(smem + 73728);
  {
    const int bsw = (lr & 7) << 3;
    const int b00 = (mh * 32 + lg * 4) ^ bsw;
    const int b10 = (mh * 32 + 16 + lg * 4) ^ bsw;
    *(f32x4*)&part[(kq * 32 + lr) * 64 + b00]      = acc00;
    *(f32x4*)&part[(kq * 32 + lr) * 64 + b10]      = acc10;
    *(f32x4*)&part[(kq * 32 + 16 + lr) * 64 + b00] = acc01;
    *(f32x4*)&part[(kq * 32 + 16 + lr) * 64 + b10] = acc11;
  }
  __syncthreads();

  {
    const int eb = tid >> 3;
    const int ej = tid & 7;
    float sum[4];
    #pragma unroll
    for (int g = 0; g < 4; ++g) {
      const int nn = g * 8 + ej;
      const int base = nn * 64 + (eb ^ (ej << 3));
      float s = 0.f;
      #pragma unroll
      for (int q = 0; q < 4; ++q) s += part[q * 2048 + base];
      sum[g] = s;
    }
    const int nbcol = cb * 8 + ej;
    const unsigned short* xrow = xg + ((long)t * 64 + eb) * 8192;
    const float iv = sum[0] + bf2f(xrow[nbcol]);
    const float fv = sum[1] + bf2f(xrow[2048 + nbcol]);
    const float gv = sum[2] + bf2f(xrow[4096 + nbcol]);
    const float ov = sum[3] + bf2f(xrow[6144 + nbcol]);
    const long ci = (long)eb * 2048 + nbcol;
    const float c = sigm(fv) * Cstate[ci] + sigm(iv) * tanh_(gv);
    const float h = sigm(ov) * tanh_(c);
    Cstate[ci] = c;
    Call_t[ci] = f2bf(c);
    Hnext[ci] = f2bf(h);
  }
}

// ---------------------------------------------------------------- heads (unchanged)
__global__ __launch_bounds__(256) void heads(
    const unsigned short* __restrict__ Hall,
    const unsigned short* __restrict__ Call,
    const float* __restrict__ Wp, const float* __restrict__ bp,
    const float* __restrict__ Wpc, const float* __restrict__ bpc,
    const float* __restrict__ Wu, const float* __restrict__ bu,
    const float* __restrict__ Wuse, const float* __restrict__ buse,
    const float* __restrict__ gum,
    float* __restrict__ out) {
  int p = blockIdx.x * 4 + (threadIdx.x >> 6);
  int l = threadIdx.x & 63;
  int t = p >> 6, b = p & 63;
  const unsigned short* h = Hall + ((long)(t + 1) * 64 + b) * 2048;
  const unsigned short* c = Call + ((long)t * 64 + b) * 2048;
  float s0 = 0, s1 = 0, sc0 = 0, sc1 = 0, su = 0, q0 = 0, q1 = 0;
  #pragma unroll
  for (int j = 0; j < 8; ++j) {
    int k = j * 256 + l * 4;
    ushort4 hv = *(const ushort4*)(h + k);
    ushort4 cv = *(const ushort4*)(c + k);
    float hf0 = bf2f(hv.x), hf1 = bf2f(hv.y), hf2 = bf2f(hv.z), hf3 = bf2f(hv.w);
    float cf0 = bf2f(cv.x), cf1 = bf2f(cv.y), cf2 = bf2f(cv.z), cf3 = bf2f(cv.w);
    float4 w0 = *(const float4*)(Wp + k);
    float4 w1 = *(const float4*)(Wp + 2048 + k);
    float4 w2 = *(const float4*)(Wpc + k);
    float4 w3 = *(const float4*)(Wpc + 2048 + k);
    float4 w4 = *(const float4*)(Wu + k);
    float4 w5 = *(const float4*)(Wuse + k);
    float4 w6 = *(const float4*)(Wuse + 2048 + k);
    s0 += hf0 * w0.x + hf1 * w0.y + hf2 * w0.z + hf3 * w0.w;
    s1 += hf0 * w1.x + hf1 * w1.y + hf2 * w1.z + hf3 * w1.w;
    sc0 += cf0 * w2.x + cf1 * w2.y + cf2 * w2.z + cf3 * w2.w;
    sc1 += cf0 * w3.x + cf1 * w3.y + cf2 * w3.z + cf3 * w3.w;
    su += hf0 * w4.x + hf1 * w4.y + hf2 * w4.z + hf3 * w4.w;
    q0 += hf0 * w5.x + hf1 * w5.y + hf2 * w5.z + hf3 * w5.w;
    q1 += hf0 * w6.x + hf1 * w6.y + hf2 * w6.z + hf3 * w6.w;
  }
  #pragma unroll
  for (int off = 32; off > 0; off >>= 1) {
    s0 += __shfl_xor(s0, off);
    s1 += __shfl_xor(s1, off);
    sc0 += __shfl_xor(sc0, off);
    sc1 += __shfl_xor(sc1, off);
    su += __shfl_xor(su, off);
    q0 += __shfl_xor(q0, off);
    q1 += __shfl_xor(q1, off);
  }
  if (l == 0) {
    out[(p << 1)] = s0 + bp[0];
    out[(p << 1) + 1] = s1 + bp[1];
    out[12288 + (p << 1)] = sc0 + bpc[0];
    out[12288 + (p << 1) + 1] = sc1 + bpc[1];
    out[24576 + p] = su + bu[0];
    float u0 = q0 + buse[0] + gum[p * 2];
    float u1 = q1 + buse[1] + gum[p * 2 + 1];
    float m = fmaxf(u0, u1);
    float x0 = expf(u0 - m), x1 = expf(u1 - m);
    float inv = 1.f / (x0 + x1);
    if (t >= 1) {
      out[30720 + ((t - 1) * 64 + b) * 2] = x0 * inv;
      out[30720 + ((t - 1) * 64 + b) * 2 + 1] = x1 * inv;
    }
  }
}

// ---------------------------------------------------------------- launch
extern "C" void kernel_launch(void* const* d_in, const int* in_sizes, int n_in,
                              void* d_out, int out_size, void* d_ws, size_t ws_size,
                              hipStream_t stream) {
  const float* feature  = (const float*)d_in[0];
  const float* W_ih     = (const float*)d_in[1];
  const float* W_hh     = (const float*)d_in[2];
  const float* b_ih     = (const float*)d_in[3];
  const float* b_hh     = (const float*)d_in[4];
  const float* W_pred   = (const float*)d_in[5];
  const float* b_pred   = (const float*)d_in[6];
  const float* W_pred_c = (const float*)d_in[7];
  const float* b_pred_c = (const float*)d_in[8];
  const float* W_util   = (const float*)d_in[9];
  const float* b_util   = (const float*)d_in[10];
  const float* W_use    = (const float*)d_in[11];
  const float* b_use    = (const float*)d_in[12];

  char* ws = (char*)d_ws;
  unsigned short* Abf  = (unsigned short*)(ws + 0);
  unsigned short* Call = (unsigned short*)(ws + 0);       // aliases Abf after phase 1
  unsigned short* Wbf  = (unsigned short*)(ws + 25165824L);
  unsigned short* xg   = (unsigned short*)(ws + 58720256L);
  unsigned short* Hall = (unsigned short*)(ws + 159383552L);
  float* Cstate        = (float*)(ws + 184811520L);
  float* gum           = (float*)(ws + 185335808L);
  float* out = (float*)d_out;

  hipMemsetAsync(Hall, 0, (size_t)BATCH * HID * 2, stream);
  hipMemsetAsync(Cstate, 0, (size_t)BATCH * HID * 4, stream);

  gumbel_k<<<48, 256, 0, stream>>>(gum);

  cast_bf16<<<(12582912 / 4) / 256, 256, 0, stream>>>(feature, Abf, 12582912 / 4);
  cast_bf16<<<(16777216 / 4) / 256, 256, 0, stream>>>(W_ih, Wbf, 16777216 / 4);

  gemm_xg<<<3072, 256, 65536, stream>>>(Abf, Wbf, b_ih, b_hh, xg);

  cast_bf16<<<(16777216 / 4) / 256, 256, 0, stream>>>(W_hh, Wbf, 16777216 / 4);

  for (int t = 0; t < T_STEPS; ++t) {
    lstm_step<<<256, 512, 0, stream>>>(
        Wbf, xg,
        Hall + (long)t * BATCH * HID,
        Hall + (long)(t + 1) * BATCH * HID,
        Call + (long)t * BATCH * HID,
        Cstate, t);
  }

  heads<<<1536, 256, 0, stream>>>(Hall, Call,
                                  W_pred, b_pred, W_pred_c, b_pred_c,
                                  W_util, b_util, W_use, b_use,
                                  gum, out);
}

// Round 15
// 1293.500 us; speedup vs baseline: 1.0391x; 1.0391x over previous
//
#include <hip/hip_runtime.h>

typedef __attribute__((ext_vector_type(8))) short bf16x8;
typedef __attribute__((ext_vector_type(4))) float f32x4;

#define T_STEPS 96
#define BATCH 64
#define HID 2048

#define AS1 __attribute__((address_space(1)))
#define AS3 __attribute__((address_space(3)))
#define MFMA16(a, b, c) __builtin_amdgcn_mfma_f32_16x16x32_bf16(a, b, c, 0, 0, 0)

__device__ inline unsigned short f2bf(float f) {
  union { float f; unsigned u; } x; x.f = f;
  unsigned r = x.u + 0x7fffu + ((x.u >> 16) & 1u);
  return (unsigned short)(r >> 16);
}
__device__ inline float bf2f(unsigned short b) {
  union { unsigned u; float f; } x; x.u = ((unsigned)b) << 16;
  return x.f;
}
__device__ inline float sigm(float x) { return 1.f / (1.f + __expf(-x)); }
__device__ inline float tanh_(float x) { return 1.f - 2.f / (__expf(2.f * x) + 1.f); }

// ---------------------------------------------------------------- cast f32->bf16
__global__ __launch_bounds__(256) void cast_bf16(const float* __restrict__ in,
                                                 unsigned short* __restrict__ out,
                                                 int n4) {
  int i = blockIdx.x * 256 + threadIdx.x;
  if (i >= n4) return;
  float4 v = ((const float4*)in)[i];
  ushort4 o;
  o.x = f2bf(v.x); o.y = f2bf(v.y); o.z = f2bf(v.z); o.w = f2bf(v.w);
  ((ushort4*)out)[i] = o;
}

// ---------------------------------------------------------------- gumbel (threefry, partitionable)
__global__ void gumbel_k(float* __restrict__ g) {
  int p = blockIdx.x * blockDim.x + threadIdx.x;
  if (p >= 12288) return;
  const unsigned k1 = 0u, k2 = 42u;
  unsigned ks[3] = { k1, k2, 0x1BD11BDAu ^ k1 ^ k2 };
  unsigned x0 = 0u + ks[0];
  unsigned x1 = (unsigned)p + ks[1];
  const int rot[2][4] = { {13, 15, 26, 6}, {17, 29, 16, 24} };
  #pragma unroll
  for (int i = 0; i < 5; ++i) {
    #pragma unroll
    for (int j = 0; j < 4; ++j) {
      int r = rot[i & 1][j];
      x0 += x1;
      x1 = (x1 << r) | (x1 >> (32 - r));
      x1 ^= x0;
    }
    x0 += ks[(i + 1) % 3];
    x1 += ks[(i + 2) % 3] + (unsigned)(i + 1);
  }
  unsigned bits = x0 ^ x1;
  union { unsigned u; float f; } v; v.u = (bits >> 9) | 0x3f800000u;
  float f = v.f - 1.f;
  const float tiny = 1.17549435e-38f;
  float u = fmaxf(tiny, f * (1.f - tiny) + tiny);
  g[p] = -logf(-logf(u));
}

// ---------------------------------------------------------------- phase-1 GEMM (R10 best: 246 us)
__global__ __launch_bounds__(512, 2) void gemm_xg(
    const unsigned short* __restrict__ A,
    const unsigned short* __restrict__ W,
    const float* __restrict__ b_ih, const float* __restrict__ b_hh,
    unsigned short* __restrict__ xg) {
  extern __shared__ unsigned char smem[];   // 128 KB = 2 dbuf x 2 khalf x (A16K|B16K)
  const int bid = blockIdx.x;
  const int swz = (bid & 7) * 96 + (bid >> 3);   // XCD-chunked, bijective (768=8*96)
  const int mb = swz >> 5, nb = swz & 31;        // 24 x 32 tiles
  const int m0 = mb * 256, n0 = nb * 256;
  const int tid = threadIdx.x;
  const int l = tid & 63;
  const int w = tid >> 6;
  const int lr = l & 15, lg = l >> 4;
  const int wm = w >> 2, wn = w & 3;

#define XSTAGE(dd, hh, tt) do {                                                 \
    _Pragma("unroll")                                                           \
    for (int r_ = 0; r_ < 2; ++r_) {                                            \
      int slot_ = r_ * 512 + tid;                                               \
      int row_ = slot_ >> 2;                                                    \
      int kby_ = ((slot_ & 3) * 16) ^ ((row_ & 3) << 4);                        \
      const unsigned short* sa_ =                                               \
          A + (long)(m0 + row_) * 2048 + (tt) * 64 + (hh) * 32 + (kby_ >> 1);   \
      __builtin_amdgcn_global_load_lds((const AS1 unsigned int*)sa_,            \
          (AS3 unsigned int*)(smem + (dd) * 65536 + (hh) * 32768 + slot_ * 16), \
          16, 0, 0);                                                            \
    }                                                                           \
    _Pragma("unroll")                                                           \
    for (int r_ = 0; r_ < 2; ++r_) {                                            \
      int slot_ = r_ * 512 + tid;                                               \
      int row_ = slot_ >> 2;                                                    \
      int kby_ = ((slot_ & 3) * 16) ^ ((row_ & 3) << 4);                        \
      const unsigned short* sb_ =                                               \
          W + (long)(n0 + row_) * 2048 + (tt) * 64 + (hh) * 32 + (kby_ >> 1);   \
      __builtin_amdgcn_global_load_lds((const AS1 unsigned int*)sb_,            \
          (AS3 unsigned int*)(smem + (dd) * 65536 + (hh) * 32768 + 16384 +      \
                              slot_ * 16), 16, 0, 0);                           \
    }                                                                           \
  } while (0)

  f32x4 acc[8][4] = {};
  const int kxa = (lr & 3) << 4;

#define XPHASE(dd, hh) do {                                                     \
    const unsigned char* ba_ = smem + (dd) * 65536 + (hh) * 32768;              \
    const unsigned char* bb_ = ba_ + 16384;                                     \
    bf16x8 a_[8], b_[4];                                                        \
    _Pragma("unroll")                                                           \
    for (int mf_ = 0; mf_ < 8; ++mf_)                                           \
      a_[mf_] = *(const bf16x8*)(ba_ + (wm * 128 + mf_ * 16 + lr) * 64 +        \
                                 ((lg * 16) ^ kxa));                            \
    _Pragma("unroll")                                                           \
    for (int nf_ = 0; nf_ < 4; ++nf_)                                           \
      b_[nf_] = *(const bf16x8*)(bb_ + (wn * 64 + nf_ * 16 + lr) * 64 +         \
                                 ((lg * 16) ^ kxa));                            \
    __builtin_amdgcn_s_setprio(1);                                              \
    _Pragma("unroll")                                                           \
    for (int mf_ = 0; mf_ < 8; ++mf_)                                           \
      _Pragma("unroll")                                                         \
      for (int nf_ = 0; nf_ < 4; ++nf_)                                         \
        acc[mf_][nf_] = MFMA16(a_[mf_], b_[nf_], acc[mf_][nf_]);                \
    __builtin_amdgcn_s_setprio(0);                                              \
    __builtin_amdgcn_sched_barrier(0);                                          \
  } while (0)

  XSTAGE(0, 0, 0);
  XSTAGE(0, 1, 0);
  __builtin_amdgcn_sched_barrier(0);

  for (int t = 0; t < 32; ++t) {
    const int d = t & 1;
    asm volatile("s_waitcnt vmcnt(4)" ::: "memory");
    __builtin_amdgcn_s_barrier();
    __builtin_amdgcn_sched_barrier(0);
    XSTAGE(d ^ 1, 0, t + 1);
    XSTAGE(d ^ 1, 1, t + 1);
    __builtin_amdgcn_sched_barrier(0);
    XPHASE(d, 0);
    asm volatile("s_waitcnt vmcnt(8)" ::: "memory");
    __builtin_amdgcn_s_barrier();
    __builtin_amdgcn_sched_barrier(0);
    XPHASE(d, 1);
  }
#undef XSTAGE
#undef XPHASE

  float bias[4];
  #pragma unroll
  for (int nf = 0; nf < 4; ++nf) {
    int n = n0 + wn * 64 + nf * 16 + lr;
    bias[nf] = b_ih[n] + b_hh[n];
  }
  #pragma unroll
  for (int mf = 0; mf < 8; ++mf) {
    #pragma unroll
    for (int r = 0; r < 4; ++r) {
      int m = m0 + wm * 128 + mf * 16 + lg * 4 + r;
      int bb2 = m / 96;
      int tt = m - bb2 * 96;
      long row = (long)tt * 64 + bb2;
      #pragma unroll
      for (int nf = 0; nf < 4; ++nf) {
        int n = n0 + wn * 64 + nf * 16 + lr;
        xg[row * 8192 + n] = f2bf(acc[mf][nf][r] + bias[nf]);
      }
    }
  }
}

// ---------------------------------------------------------------- recurrent step (R13 best)
__global__ __launch_bounds__(512) void lstm_step(
    const unsigned short* __restrict__ Whh,   // (8192,2048) bf16
    const unsigned short* __restrict__ xg,    // (96,64,8192) bf16
    const unsigned short* __restrict__ Hprev, // (64,2048) bf16
    unsigned short* __restrict__ Hnext,       // (64,2048) bf16
    unsigned short* __restrict__ Call_t,      // (64,2048) bf16 snapshot
    float* __restrict__ Cstate,               // (64,2048) f32
    int t) {
  __shared__ unsigned char smem[3 * 24576 + 32768];  // ring (A16K+B8K per buf) + part 32K
  const int cb = blockIdx.x;
  const int tid = threadIdx.x;
  const int w = tid >> 6, l = tid & 63;
  const int lr = l & 15, lg = l >> 4;
  const int mh = w & 1, kq = w >> 1;

  const int lane16 = l & 15, lrow = l >> 4;
  const int rowA0 = w * 4 + lrow;
  const int rowA1 = 32 + rowA0;
  const int rowB  = w * 4 + lrow;
  const int kszA0 = (lane16 * 16) ^ ((rowA0 & 7) << 4);
  const int kszA1 = (lane16 * 16) ^ ((rowA1 & 7) << 4);
  const int kszB  = (lane16 * 16) ^ ((rowB & 7) << 4);
  const int WrowB = (rowB >> 3) * 2048 + cb * 8 + (rowB & 7);
  const unsigned short* aS0 = Hprev + (long)rowA0 * 2048 + (kszA0 >> 1);
  const unsigned short* aS1 = Hprev + (long)rowA1 * 2048 + (kszA1 >> 1);
  const unsigned short* bS  = Whh + (long)WrowB * 2048 + (kszB >> 1);

#define STAGE(bufi, k0) do {                                                    \
    unsigned char* lb = smem + (bufi) * 24576 + w * 1024;                       \
    __builtin_amdgcn_global_load_lds((const AS1 unsigned int*)(aS0 + (k0)),     \
        (AS3 unsigned int*)(lb), 16, 0, 0);                                     \
    __builtin_amdgcn_global_load_lds((const AS1 unsigned int*)(aS1 + (k0)),     \
        (AS3 unsigned int*)(lb + 8192), 16, 0, 0);                              \
    __builtin_amdgcn_global_load_lds((const AS1 unsigned int*)(bS + (k0)),      \
        (AS3 unsigned int*)(lb + 16384), 16, 0, 0);                             \
  } while (0)

  STAGE(0, 0);
  STAGE(1, 128);

  f32x4 acc00 = {}, acc01 = {}, acc10 = {}, acc11 = {};
  const int kx = (lr & 7) << 4;
  const int aOff0 = (mh * 32 + lr) * 256;
  const int aOff1 = (mh * 32 + 16 + lr) * 256;
  const int bOff0 = 16384 + lr * 256;
  const int bOff1 = 16384 + (16 + lr) * 256;
  const int kb = (kq * 64 + lg * 16) ^ kx;

  for (int ks = 0; ks < 16; ++ks) {
    if (ks < 15) asm volatile("s_waitcnt vmcnt(3)" ::: "memory");
    else         asm volatile("s_waitcnt vmcnt(0)" ::: "memory");
    __builtin_amdgcn_s_barrier();
    __builtin_amdgcn_sched_barrier(0);
    if (ks < 14) STAGE((ks + 2) % 3, (ks + 2) * 128);
    const unsigned char* bufp = smem + (ks % 3) * 24576;
    __builtin_amdgcn_s_setprio(1);
    {
      bf16x8 a0 = *(const bf16x8*)(bufp + aOff0 + kb);
      bf16x8 a1 = *(const bf16x8*)(bufp + aOff1 + kb);
      bf16x8 b0 = *(const bf16x8*)(bufp + bOff0 + kb);
      bf16x8 b1 = *(const bf16x8*)(bufp + bOff1 + kb);
      acc00 = MFMA16(a0, b0, acc00);
      acc01 = MFMA16(a0, b1, acc01);
      acc10 = MFMA16(a1, b0, acc10);
      acc11 = MFMA16(a1, b1, acc11);
    }
    __builtin_amdgcn_s_setprio(0);
    __builtin_amdgcn_sched_barrier(0);
  }
#undef STAGE

  float* part = (float*)(smem + 73728);
  {
    const int bsw = (lr & 7) << 3;
    const int b00 = (mh * 32 + lg * 4) ^ bsw;
    const int b10 = (mh * 32 + 16 + lg * 4) ^ bsw;
    *(f32x4*)&part[(kq * 32 + lr) * 64 + b00]      = acc00;
    *(f32x4*)&part[(kq * 32 + lr) * 64 + b10]      = acc10;
    *(f32x4*)&part[(kq * 32 + 16 + lr) * 64 + b00] = acc01;
    *(f32x4*)&part[(kq * 32 + 16 + lr) * 64 + b10] = acc11;
  }
  __syncthreads();

  {
    const int eb = tid >> 3;
    const int ej = tid & 7;
    float sum[4];
    #pragma unroll
    for (int g = 0; g < 4; ++g) {
      const int nn = g * 8 + ej;
      const int base = nn * 64 + (eb ^ (ej << 3));
      float s = 0.f;
      #pragma unroll
      for (int q = 0; q < 4; ++q) s += part[q * 2048 + base];
      sum[g] = s;
    }
    const int nbcol = cb * 8 + ej;
    const unsigned short* xrow = xg + ((long)t * 64 + eb) * 8192;
    const float iv = sum[0] + bf2f(xrow[nbcol]);
    const float fv = sum[1] + bf2f(xrow[2048 + nbcol]);
    const float gv = sum[2] + bf2f(xrow[4096 + nbcol]);
    const float ov = sum[3] + bf2f(xrow[6144 + nbcol]);
    const long ci = (long)eb * 2048 + nbcol;
    const float cprev = (t == 0) ? 0.f : Cstate[ci];   // no Cstate memset needed
    const float c = sigm(fv) * cprev + sigm(iv) * tanh_(gv);
    const float h = sigm(ov) * tanh_(c);
    Cstate[ci] = c;
    Call_t[ci] = f2bf(c);
    Hnext[ci] = f2bf(h);
  }
}

// ---------------------------------------------------------------- heads (unchanged)
__global__ __launch_bounds__(256) void heads(
    const unsigned short* __restrict__ Hall,
    const unsigned short* __restrict__ Call,
    const float* __restrict__ Wp, const float* __restrict__ bp,
    const float* __restrict__ Wpc, const float* __restrict__ bpc,
    const float* __restrict__ Wu, const float* __restrict__ bu,
    const float* __restrict__ Wuse, const float* __restrict__ buse,
    const float* __restrict__ gum,
    float* __restrict__ out) {
  int p = blockIdx.x * 4 + (threadIdx.x >> 6);
  int l = threadIdx.x & 63;
  int t = p >> 6, b = p & 63;
  const unsigned short* h = Hall + ((long)(t + 1) * 64 + b) * 2048;
  const unsigned short* c = Call + ((long)t * 64 + b) * 2048;
  float s0 = 0, s1 = 0, sc0 = 0, sc1 = 0, su = 0, q0 = 0, q1 = 0;
  #pragma unroll
  for (int j = 0; j < 8; ++j) {
    int k = j * 256 + l * 4;
    ushort4 hv = *(const ushort4*)(h + k);
    ushort4 cv = *(const ushort4*)(c + k);
    float hf0 = bf2f(hv.x), hf1 = bf2f(hv.y), hf2 = bf2f(hv.z), hf3 = bf2f(hv.w);
    float cf0 = bf2f(cv.x), cf1 = bf2f(cv.y), cf2 = bf2f(cv.z), cf3 = bf2f(cv.w);
    float4 w0 = *(const float4*)(Wp + k);
    float4 w1 = *(const float4*)(Wp + 2048 + k);
    float4 w2 = *(const float4*)(Wpc + k);
    float4 w3 = *(const float4*)(Wpc + 2048 + k);
    float4 w4 = *(const float4*)(Wu + k);
    float4 w5 = *(const float4*)(Wuse + k);
    float4 w6 = *(const float4*)(Wuse + 2048 + k);
    s0 += hf0 * w0.x + hf1 * w0.y + hf2 * w0.z + hf3 * w0.w;
    s1 += hf0 * w1.x + hf1 * w1.y + hf2 * w1.z + hf3 * w1.w;
    sc0 += cf0 * w2.x + cf1 * w2.y + cf2 * w2.z + cf3 * w2.w;
    sc1 += cf0 * w3.x + cf1 * w3.y + cf2 * w3.z + cf3 * w3.w;
    su += hf0 * w4.x + hf1 * w4.y + hf2 * w4.z + hf3 * w4.w;
    q0 += hf0 * w5.x + hf1 * w5.y + hf2 * w5.z + hf3 * w5.w;
    q1 += hf0 * w6.x + hf1 * w6.y + hf2 * w6.z + hf3 * w6.w;
  }
  #pragma unroll
  for (int off = 32; off > 0; off >>= 1) {
    s0 += __shfl_xor(s0, off);
    s1 += __shfl_xor(s1, off);
    sc0 += __shfl_xor(sc0, off);
    sc1 += __shfl_xor(sc1, off);
    su += __shfl_xor(su, off);
    q0 += __shfl_xor(q0, off);
    q1 += __shfl_xor(q1, off);
  }
  if (l == 0) {
    out[(p << 1)] = s0 + bp[0];
    out[(p << 1) + 1] = s1 + bp[1];
    out[12288 + (p << 1)] = sc0 + bpc[0];
    out[12288 + (p << 1) + 1] = sc1 + bpc[1];
    out[24576 + p] = su + bu[0];
    float u0 = q0 + buse[0] + gum[p * 2];
    float u1 = q1 + buse[1] + gum[p * 2 + 1];
    float m = fmaxf(u0, u1);
    float x0 = expf(u0 - m), x1 = expf(u1 - m);
    float inv = 1.f / (x0 + x1);
    if (t >= 1) {
      out[30720 + ((t - 1) * 64 + b) * 2] = x0 * inv;
      out[30720 + ((t - 1) * 64 + b) * 2 + 1] = x1 * inv;
    }
  }
}

// ---------------------------------------------------------------- launch
extern "C" void kernel_launch(void* const* d_in, const int* in_sizes, int n_in,
                              void* d_out, int out_size, void* d_ws, size_t ws_size,
                              hipStream_t stream) {
  const float* feature  = (const float*)d_in[0];
  const float* W_ih     = (const float*)d_in[1];
  const float* W_hh     = (const float*)d_in[2];
  const float* b_ih     = (const float*)d_in[3];
  const float* b_hh     = (const float*)d_in[4];
  const float* W_pred   = (const float*)d_in[5];
  const float* b_pred   = (const float*)d_in[6];
  const float* W_pred_c = (const float*)d_in[7];
  const float* b_pred_c = (const float*)d_in[8];
  const float* W_util   = (const float*)d_in[9];
  const float* b_util   = (const float*)d_in[10];
  const float* W_use    = (const float*)d_in[11];
  const float* b_use    = (const float*)d_in[12];

  char* ws = (char*)d_ws;
  unsigned short* Abf  = (unsigned short*)(ws + 0);
  unsigned short* Call = (unsigned short*)(ws + 0);       // aliases Abf after phase 1
  unsigned short* Wbf  = (unsigned short*)(ws + 25165824L);
  unsigned short* xg   = (unsigned short*)(ws + 58720256L);
  unsigned short* Hall = (unsigned short*)(ws + 159383552L);
  float* Cstate        = (float*)(ws + 184811520L);
  float* gum           = (float*)(ws + 185335808L);
  float* out = (float*)d_out;

  hipMemsetAsync(Hall, 0, (size_t)BATCH * HID * 2, stream);

  gumbel_k<<<48, 256, 0, stream>>>(gum);

  cast_bf16<<<(12582912 / 4) / 256, 256, 0, stream>>>(feature, Abf, 12582912 / 4);
  cast_bf16<<<(16777216 / 4) / 256, 256, 0, stream>>>(W_ih, Wbf, 16777216 / 4);

  gemm_xg<<<768, 512, 131072, stream>>>(Abf, Wbf, b_ih, b_hh, xg);

  cast_bf16<<<(16777216 / 4) / 256, 256, 0, stream>>>(W_hh, Wbf, 16777216 / 4);

  for (int t = 0; t < T_STEPS; ++t) {
    lstm_step<<<256, 512, 0, stream>>>(
        Wbf, xg,
        Hall + (long)t * BATCH * HID,
        Hall + (long)(t + 1) * BATCH * HID,
        Call + (long)t * BATCH * HID,
        Cstate, t);
  }

  heads<<<1536, 256, 0, stream>>>(Hall, Call,
                                  W_pred, b_pred, W_pred_c, b_pred_c,
                                  W_util, b_util, W_use, b_use,
                                  gum, out);
}